// Round 3
// baseline (266.549 us; speedup 1.0000x reference)
//
#include <hip/hip_runtime.h>
#include <math.h>

// GATv2 (in_ch=1, edge_dim=1, H=2, C=64) + fc, collapsed to rank-1/rank-2 algebra.
//
// Round 3: linked-list scatter — ONE random transaction per edge (atomicExch on
// head) + coalesced 16B record write. k_node walks 4 lists/node with 4 threads
// per node (shfl combine). k_detect/k_const folded into k_prep / k_out.
//
// ws layout (floats):
//   [0, 4N)          int  head[4n+q]   (memset 0xFF => -1)
//   [4N, 6N)         float S[2n+h]
//   [6N, 6N+1152)    consts: A1,A2,BASE,U0,U1,V0,V1,CB (8x128), flag at +1024
//   [6N+1152, +4E)   int4 rec[e] = {next, exp0_bits, exp1_bits, xsrc_bits}

#define LRELU_A1 0.6f   // leakyrelu(v) = 0.6 v + 0.4 |v|  (slope 0.2)
#define LRELU_A2 0.4f

__global__ void k_prep(const unsigned int* __restrict__ ei,
                       const float* __restrict__ att,
                       const float* __restrict__ W_l,
                       const float* __restrict__ b_l, const float* __restrict__ b_r,
                       const float* __restrict__ bias_out,
                       const float* __restrict__ W_fc, const float* __restrict__ b_fc,
                       float* __restrict__ C) {
  int j = threadIdx.x;
  if (j == 128) {  // int64-vs-int32 edge_index detect (little-endian high words)
    int z = 1;
    for (int i = 0; i < 32; i++) if (ei[2 * i + 1] != 0u) { z = 0; break; }
    ((int*)C)[1024] = z;
  }
  if (j >= 128) return;
  float a = att[j];
  C[j] = LRELU_A1 * a;          // A1
  C[128 + j] = LRELU_A2 * a;    // A2
  C[256 + j] = b_l[j] + b_r[j]; // BASE
  const float* wrow = W_fc + j * 256;
  float u0 = 0.f, u1 = 0.f, v0 = 0.f, v1 = 0.f, cb = b_fc[j];
  for (int c = 0; c < 64; c++) {
    u0 = fmaf(W_l[c],      wrow[c],       u0);
    u1 = fmaf(W_l[64 + c], wrow[64 + c],  u1);
    v0 = fmaf(W_l[c],      wrow[128 + c], v0);
    v1 = fmaf(W_l[64 + c], wrow[192 + c], v1);
  }
  for (int t = 0; t < 128; t++) {
    float gb = b_l[t] + bias_out[t];
    cb = fmaf(gb, wrow[t] + wrow[128 + t], cb);
  }
  C[384 + j] = u0;  // U0
  C[512 + j] = u1;  // U1
  C[640 + j] = v0;  // V0
  C[768 + j] = v1;  // V1
  C[896 + j] = cb;  // CB
}

#define CH_STEP(comp, ACC, i)                                                      \
  do {                                                                             \
    float v_ = fmaf(xs8[i], wl.comp, fmaf(xt8[i], wr.comp, fmaf(ae8[i], we.comp, bb.comp))); \
    ACC[i] = fmaf(a2.comp, fabsf(v_), fmaf(a1.comp, v_, ACC[i]));                  \
  } while (0)

__global__ __launch_bounds__(256) void k_edge(
    const float* __restrict__ x, const int* __restrict__ ei,
    const float* __restrict__ ea,
    const float* __restrict__ WL, const float* __restrict__ WR,
    const float* __restrict__ WE,
    const float* __restrict__ C,
    int* __restrict__ head, int4* __restrict__ rec, int E) {
  int t = blockIdx.x * blockDim.x + threadIdx.x;
  int e0 = t * 8;
  if (e0 >= E) return;
  const bool w64 = ((const int*)C)[1024] != 0;
  const float* A1 = C;
  const float* A2 = C + 128;
  const float* BASE = C + 256;
  int de[8];
  float ae8[8], xs8[8], xt8[8];
  bool ok[8];
#pragma unroll
  for (int i = 0; i < 8; i++) {
    int e = e0 + i;
    ok[i] = (e < E);
    int ee = ok[i] ? e : e0;
    int s_ = w64 ? ei[2 * ee] : ei[ee];
    int d_ = w64 ? ei[2 * (E + ee)] : ei[E + ee];
    de[i] = d_;
    ae8[i] = ea[ee];
    xs8[i] = x[s_];
    xt8[i] = x[d_];
  }
  float acc0[8] = {0.f, 0.f, 0.f, 0.f, 0.f, 0.f, 0.f, 0.f};
  float acc1[8] = {0.f, 0.f, 0.f, 0.f, 0.f, 0.f, 0.f, 0.f};
#pragma unroll 2
  for (int jb = 0; jb < 64; jb += 4) {
    float4 wl = *(const float4*)(WL + jb);
    float4 wr = *(const float4*)(WR + jb);
    float4 we = *(const float4*)(WE + jb);
    float4 bb = *(const float4*)(BASE + jb);
    float4 a1 = *(const float4*)(A1 + jb);
    float4 a2 = *(const float4*)(A2 + jb);
#pragma unroll
    for (int i = 0; i < 8; i++) {
      CH_STEP(x, acc0, i); CH_STEP(y, acc0, i); CH_STEP(z, acc0, i); CH_STEP(w, acc0, i);
    }
  }
#pragma unroll 2
  for (int jb = 64; jb < 128; jb += 4) {
    float4 wl = *(const float4*)(WL + jb);
    float4 wr = *(const float4*)(WR + jb);
    float4 we = *(const float4*)(WE + jb);
    float4 bb = *(const float4*)(BASE + jb);
    float4 a1 = *(const float4*)(A1 + jb);
    float4 a2 = *(const float4*)(A2 + jb);
#pragma unroll
    for (int i = 0; i < 8; i++) {
      CH_STEP(x, acc1, i); CH_STEP(y, acc1, i); CH_STEP(z, acc1, i); CH_STEP(w, acc1, i);
    }
  }
  int prev[8];
#pragma unroll
  for (int i = 0; i < 8; i++) {
    if (ok[i]) prev[i] = atomicExch(&head[4 * de[i] + ((e0 + i) & 3)], e0 + i);
  }
#pragma unroll
  for (int i = 0; i < 8; i++) {
    if (ok[i]) {
      rec[e0 + i] = make_int4(prev[i],
                              __float_as_int(__expf(acc0[i])),
                              __float_as_int(__expf(acc1[i])),
                              __float_as_int(xs8[i]));
    }
  }
}

__global__ __launch_bounds__(256) void k_node(
    const float* __restrict__ x, const float* __restrict__ ea,
    const float* __restrict__ WL, const float* __restrict__ WR,
    const float* __restrict__ WE,
    const float* __restrict__ C,
    const int* __restrict__ head, const int4* __restrict__ rec,
    float* __restrict__ S, int N) {
  int g = blockIdx.x * blockDim.x + threadIdx.x;
  int n = g >> 2;
  if (n >= N) return;
  int q = g & 3;
  const float* A1 = C;
  const float* A2 = C + 128;
  const float* BASE = C + 256;
  int p = head[4 * n + q];
  float den0 = 0.f, num0 = 0.f, den1 = 0.f, num1 = 0.f, asum = 0.f;
  float cnt = 0.f;
  while (p >= 0) {
    int4 r = rec[p];
    float aev = ea[p];
    float e0 = __int_as_float(r.y);
    float e1 = __int_as_float(r.z);
    float xv = __int_as_float(r.w);
    den0 += e0; num0 += e0 * xv;
    den1 += e1; num1 += e1 * xv;
    asum += aev; cnt += 1.f;
    p = r.x;
  }
#pragma unroll
  for (int off = 1; off < 4; off <<= 1) {
    den0 += __shfl_xor(den0, off);
    num0 += __shfl_xor(num0, off);
    den1 += __shfl_xor(den1, off);
    num1 += __shfl_xor(num1, off);
    asum += __shfl_xor(asum, off);
    cnt  += __shfl_xor(cnt,  off);
  }
  if (q != 0) return;
  float xn = x[n];
  float am = asum / fmaxf(cnt, 1.0f);
  float acc0 = 0.f, acc1 = 0.f;
#pragma unroll 4
  for (int jb = 0; jb < 64; jb += 4) {
    float4 wl = *(const float4*)(WL + jb);
    float4 wr = *(const float4*)(WR + jb);
    float4 we = *(const float4*)(WE + jb);
    float4 bb = *(const float4*)(BASE + jb);
    float4 a1 = *(const float4*)(A1 + jb);
    float4 a2 = *(const float4*)(A2 + jb);
    float v;
    v = fmaf(xn, wl.x + wr.x, fmaf(am, we.x, bb.x)); acc0 = fmaf(a2.x, fabsf(v), fmaf(a1.x, v, acc0));
    v = fmaf(xn, wl.y + wr.y, fmaf(am, we.y, bb.y)); acc0 = fmaf(a2.y, fabsf(v), fmaf(a1.y, v, acc0));
    v = fmaf(xn, wl.z + wr.z, fmaf(am, we.z, bb.z)); acc0 = fmaf(a2.z, fabsf(v), fmaf(a1.z, v, acc0));
    v = fmaf(xn, wl.w + wr.w, fmaf(am, we.w, bb.w)); acc0 = fmaf(a2.w, fabsf(v), fmaf(a1.w, v, acc0));
  }
#pragma unroll 4
  for (int jb = 64; jb < 128; jb += 4) {
    float4 wl = *(const float4*)(WL + jb);
    float4 wr = *(const float4*)(WR + jb);
    float4 we = *(const float4*)(WE + jb);
    float4 bb = *(const float4*)(BASE + jb);
    float4 a1 = *(const float4*)(A1 + jb);
    float4 a2 = *(const float4*)(A2 + jb);
    float v;
    v = fmaf(xn, wl.x + wr.x, fmaf(am, we.x, bb.x)); acc1 = fmaf(a2.x, fabsf(v), fmaf(a1.x, v, acc1));
    v = fmaf(xn, wl.y + wr.y, fmaf(am, we.y, bb.y)); acc1 = fmaf(a2.y, fabsf(v), fmaf(a1.y, v, acc1));
    v = fmaf(xn, wl.z + wr.z, fmaf(am, we.z, bb.z)); acc1 = fmaf(a2.z, fabsf(v), fmaf(a1.z, v, acc1));
    v = fmaf(xn, wl.w + wr.w, fmaf(am, we.w, bb.w)); acc1 = fmaf(a2.w, fabsf(v), fmaf(a1.w, v, acc1));
  }
  float s0 = __expf(acc0), s1 = __expf(acc1);
  float2 sv;
  sv.x = (num0 + s0 * xn) / (den0 + s0);
  sv.y = (num1 + s1 * xn) / (den1 + s1);
  *(float2*)(S + 2 * n) = sv;
}

__global__ __launch_bounds__(256) void k_out(
    const float* __restrict__ S, const float* __restrict__ C,
    const int* __restrict__ tgtp, float* __restrict__ out, int N) {
  int g = blockIdx.x * blockDim.x + threadIdx.x;
  if (g >= N * 32) return;
  int n = g >> 5;
  int kq = (g & 31) * 4;
  int T = tgtp[0];  // low word valid for int32 and little-endian int64
  float s0t = S[2 * T], s1t = S[2 * T + 1];
  float2 s = *(const float2*)(S + 2 * n);
  float4 u0 = *(const float4*)(C + 384 + kq);
  float4 u1 = *(const float4*)(C + 512 + kq);
  float4 v0 = *(const float4*)(C + 640 + kq);
  float4 v1 = *(const float4*)(C + 768 + kq);
  float4 cb = *(const float4*)(C + 896 + kq);
  float4 o;
  o.x = fmaf(s.x, u0.x, fmaf(s.y, u1.x, fmaf(s0t, v0.x, fmaf(s1t, v1.x, cb.x))));
  o.y = fmaf(s.x, u0.y, fmaf(s.y, u1.y, fmaf(s0t, v0.y, fmaf(s1t, v1.y, cb.y))));
  o.z = fmaf(s.x, u0.z, fmaf(s.y, u1.z, fmaf(s0t, v0.z, fmaf(s1t, v1.z, cb.z))));
  o.w = fmaf(s.x, u0.w, fmaf(s.y, u1.w, fmaf(s0t, v0.w, fmaf(s1t, v1.w, cb.w))));
  *(float4*)(out + n * 128 + kq) = o;
}

extern "C" void kernel_launch(void* const* d_in, const int* in_sizes, int n_in,
                              void* d_out, int out_size, void* d_ws, size_t ws_size,
                              hipStream_t stream) {
  const float* x        = (const float*)d_in[0];
  const int*   ei       = (const int*)d_in[1];
  const float* ea       = (const float*)d_in[2];
  const int*   tgt      = (const int*)d_in[3];
  const float* W_l      = (const float*)d_in[4];
  const float* b_l      = (const float*)d_in[5];
  const float* W_r      = (const float*)d_in[6];
  const float* b_r      = (const float*)d_in[7];
  const float* W_e      = (const float*)d_in[8];
  const float* att      = (const float*)d_in[9];
  const float* bias_out = (const float*)d_in[10];
  const float* W_fc     = (const float*)d_in[11];
  const float* b_fc     = (const float*)d_in[12];

  const int N = in_sizes[0];
  const int E = in_sizes[2];

  float* ws   = (float*)d_ws;
  int*   head = (int*)ws;                      // 4N ints
  float* S    = ws + (size_t)4 * N;            // 2N floats
  float* C    = ws + (size_t)6 * N;            // 1152 floats (consts + flag)
  int4*  rec  = (int4*)(ws + (size_t)6 * N + 1152);  // E recs (16B each)

  hipMemsetAsync(head, 0xFF, sizeof(int) * (size_t)4 * N, stream);
  k_prep<<<1, 192, 0, stream>>>((const unsigned int*)ei, att, W_l, b_l, b_r,
                                bias_out, W_fc, b_fc, C);

  int nt = (E + 7) / 8;
  k_edge<<<(nt + 255) / 256, 256, 0, stream>>>(x, ei, ea, W_l, W_r, W_e, C,
                                               head, rec, E);
  k_node<<<(N * 4 + 255) / 256, 256, 0, stream>>>(x, ea, W_l, W_r, W_e, C,
                                                  head, rec, S, N);
  k_out<<<(N * 32 + 255) / 256, 256, 0, stream>>>(S, C, tgt, (float*)d_out, N);
}